// Round 1
// baseline (12.056 us; speedup 1.0000x reference)
//
#include <hip/hip_runtime.h>
#include <math.h>

#define ALPHA 0.1f
#define DDIM 128
#define KTRUNC 256

__global__ __launch_bounds__(256) void pop_predict_kernel(
    const float* __restrict__ pop_history,   // [B,T]
    const float* __restrict__ rating_number, // [B]
    const int*   __restrict__ item_ids,      // [B]
    const int*   __restrict__ times,         // [B]
    const int*   __restrict__ release_times, // [B]
    const int*   __restrict__ categories,    // [B]
    const int*   __restrict__ stores,        // [B]
    const float* __restrict__ item_emb,      // [NUM_ITEMS+1, D]
    const float* __restrict__ cat_emb,       // [NUM_CATS+1, D]
    const float* __restrict__ store_emb,     // [NUM_STORES, D]
    const float* __restrict__ time_emb,      // [MAX_TIME+1, D]
    const float* __restrict__ W_rating,      // [D]
    const float* __restrict__ b_rating,      // [D]
    const float* __restrict__ W_side,        // [3D]
    const float* __restrict__ b_side,        // [1]
    const float* __restrict__ W_time,        // [4D]
    const float* __restrict__ b_time,        // [1]
    const float* __restrict__ att_w,         // [3]
    float* __restrict__ out,                 // [4B] = pop | time | side | mix
    int B, int T)
{
    const int wave = threadIdx.x >> 6;
    const int lane = threadIdx.x & 63;
    const int b = blockIdx.x * 4 + wave;
    if (b >= B) return;

    // ---- EMA at tb = clip(times[b]-1, 0), truncated to last KTRUNC terms ----
    int t = times[b] - 1; if (t < 0) t = 0;
    int start = t - (KTRUNC - 1); if (start < 0) start = 0;
    const float LOG2_09 = -0.15200309344504995f; // log2(0.9)
    float ema = 0.f;
    const float* ph = pop_history + (size_t)b * (size_t)T;
    for (int k = start + lane; k <= t; k += 64) {
        // e_t = 0.9^t * p_0 + sum_{k>=1} 0.1 * 0.9^(t-k) * p_k
        float coef = (k == 0) ? exp2f((float)t * LOG2_09)
                              : ALPHA * exp2f((float)(t - k) * LOG2_09);
        ema += coef * ph[k];
    }

    // ---- embedding gathers + dot products (2 dims per lane) ----
    const int ii = item_ids[b];
    const int ti = times[b];
    const int ri = release_times[b];
    const int ci = categories[b];
    const int si = stores[b];
    const float rating = rating_number[b];

    float tdot = 0.f, sdot = 0.f;
    #pragma unroll
    for (int j = 0; j < 2; ++j) {
        const int d = lane + j * 64;
        const float ie = item_emb[(size_t)ii * DDIM + d];
        const float te = time_emb[(size_t)ti * DDIM + d];
        const float re = time_emb[(size_t)ri * DDIM + d];
        const float ce = cat_emb[(size_t)ci * DDIM + d];
        const float se = store_emb[(size_t)si * DDIM + d];
        const float gap = re - te;
        tdot += gap * W_time[d] + ie * W_time[DDIM + d]
              + te * W_time[2 * DDIM + d] + re * W_time[3 * DDIM + d];
        const float r = rating * W_rating[d] + b_rating[d];
        sdot += r * W_side[d] + ce * W_side[DDIM + d] + se * W_side[2 * DDIM + d];
    }

    // ---- 64-lane butterfly reduction of the three partials ----
    #pragma unroll
    for (int off = 32; off >= 1; off >>= 1) {
        ema  += __shfl_xor(ema,  off);
        tdot += __shfl_xor(tdot, off);
        sdot += __shfl_xor(sdot, off);
    }

    if (lane == 0) {
        const float pop = 1.f / (1.f + expf(-ema));

        float tv = tdot + b_time[0];
        tv = (tv >= 0.f) ? tv : 0.01f * tv;     // LeakyReLU(0.01)
        const float tim = 1.f / (1.f + expf(-tv));

        const float sv  = sdot + b_side[0];
        const float sid = 1.f / (1.f + expf(-sv));

        // softmax over att_w[3]
        const float a0 = att_w[0], a1 = att_w[1], a2 = att_w[2];
        const float m  = fmaxf(a0, fmaxf(a1, a2));
        const float e0 = expf(a0 - m), e1 = expf(a1 - m), e2 = expf(a2 - m);
        const float inv = 1.f / (e0 + e1 + e2);
        const float mix = (pop * e0 + tim * e1 + sid * e2) * inv;

        out[b]         = pop;
        out[B + b]     = tim;
        out[2 * B + b] = sid;
        out[3 * B + b] = mix;
    }
}

extern "C" void kernel_launch(void* const* d_in, const int* in_sizes, int n_in,
                              void* d_out, int out_size, void* d_ws, size_t ws_size,
                              hipStream_t stream) {
    const float* pop_history   = (const float*)d_in[0];
    const float* rating_number = (const float*)d_in[1];
    const int*   item_ids      = (const int*)d_in[2];
    const int*   times         = (const int*)d_in[3];
    const int*   release_times = (const int*)d_in[4];
    const int*   categories    = (const int*)d_in[5];
    const int*   stores        = (const int*)d_in[6];
    const float* item_emb      = (const float*)d_in[7];
    const float* cat_emb       = (const float*)d_in[8];
    const float* store_emb     = (const float*)d_in[9];
    const float* time_emb      = (const float*)d_in[10];
    const float* W_rating      = (const float*)d_in[11];
    const float* b_rating      = (const float*)d_in[12];
    const float* W_side        = (const float*)d_in[13];
    const float* b_side        = (const float*)d_in[14];
    const float* W_time        = (const float*)d_in[15];
    const float* b_time        = (const float*)d_in[16];
    const float* att_w         = (const float*)d_in[17];

    const int B = in_sizes[1];              // rating_number is [B]
    const int T = in_sizes[0] / B;          // pop_history is [B,T]

    const int rows_per_block = 4;           // 4 waves of 64
    const int grid = (B + rows_per_block - 1) / rows_per_block;
    pop_predict_kernel<<<grid, 256, 0, stream>>>(
        pop_history, rating_number, item_ids, times, release_times, categories,
        stores, item_emb, cat_emb, store_emb, time_emb,
        W_rating, b_rating, W_side, b_side, W_time, b_time, att_w,
        (float*)d_out, B, T);
}

// Round 2
// 11.709 us; speedup vs baseline: 1.0297x; 1.0297x over previous
//
#include <hip/hip_runtime.h>
#include <math.h>

#define ALPHA 0.1f
#define DDIM 128
// EMA truncation window: dropped mass = 0.9^64 ~= 1.18e-3 -> <=3e-4 output err
#define KTRUNC 64

__global__ __launch_bounds__(256) void pop_predict_kernel(
    const float* __restrict__ pop_history,   // [B,T]
    const float* __restrict__ rating_number, // [B]
    const int*   __restrict__ item_ids,      // [B]
    const int*   __restrict__ times,         // [B]
    const int*   __restrict__ release_times, // [B]
    const int*   __restrict__ categories,    // [B]
    const int*   __restrict__ stores,        // [B]
    const float* __restrict__ item_emb,      // [NUM_ITEMS+1, D]
    const float* __restrict__ cat_emb,       // [NUM_CATS+1, D]
    const float* __restrict__ store_emb,     // [NUM_STORES, D]
    const float* __restrict__ time_emb,      // [MAX_TIME+1, D]
    const float* __restrict__ W_rating,      // [D]
    const float* __restrict__ b_rating,      // [D]
    const float* __restrict__ W_side,        // [3D]
    const float* __restrict__ b_side,        // [1]
    const float* __restrict__ W_time,        // [4D]
    const float* __restrict__ b_time,        // [1]
    const float* __restrict__ att_w,         // [3]
    float* __restrict__ out,                 // [4B] = pop | time | side | mix
    int B, int T)
{
    const int wave = threadIdx.x >> 6;
    const int lane = threadIdx.x & 63;
    const int b = blockIdx.x * 4 + wave;
    if (b >= B) return;

    // ---- per-row scalars (wave-uniform -> scalar loads) ----
    const int ti = times[b];
    const int ii = item_ids[b];
    const int ri = release_times[b];
    const int ci = categories[b];
    const int si = stores[b];
    const float rating = rating_number[b];

    // ---- EMA at tb = clip(ti-1, 0), truncated to the last KTRUNC terms ----
    // e_t = 0.9^t p_0 + sum_{k>=1} 0.1*0.9^(t-k) p_k.  With k = t-63+lane,
    // t-k = 63-lane (lane-constant): coef = 0.1*0.9^(63-lane); k==0 term
    // has no alpha factor (coef *= 10).
    int t = ti - 1; if (t < 0) t = 0;
    const float LOG2_09 = -0.15200309344504995f; // log2(0.9)
    const int k = t - (KTRUNC - 1) + lane;
    float coef = ALPHA * exp2f((float)((KTRUNC - 1) - lane) * LOG2_09);
    if (k == 0) coef *= 10.f;
    float ema = 0.f;
    if (k >= 0) ema = coef * pop_history[(size_t)b * (size_t)T + k];

    // ---- embedding gathers + dot products (float2: dims 2*lane, 2*lane+1) ----
    const int d2 = lane * 2;
    const float2 ie = *(const float2*)(item_emb  + (size_t)ii * DDIM + d2);
    const float2 te = *(const float2*)(time_emb  + (size_t)ti * DDIM + d2);
    const float2 re = *(const float2*)(time_emb  + (size_t)ri * DDIM + d2);
    const float2 ce = *(const float2*)(cat_emb   + (size_t)ci * DDIM + d2);
    const float2 se = *(const float2*)(store_emb + (size_t)si * DDIM + d2);

    const float2 wt0 = *(const float2*)(W_time + d2);
    const float2 wt1 = *(const float2*)(W_time + DDIM + d2);
    const float2 wt2 = *(const float2*)(W_time + 2 * DDIM + d2);
    const float2 wt3 = *(const float2*)(W_time + 3 * DDIM + d2);
    const float2 wr  = *(const float2*)(W_rating + d2);
    const float2 br  = *(const float2*)(b_rating + d2);
    const float2 ws0 = *(const float2*)(W_side + d2);
    const float2 ws1 = *(const float2*)(W_side + DDIM + d2);
    const float2 ws2 = *(const float2*)(W_side + 2 * DDIM + d2);

    const float gx = re.x - te.x, gy = re.y - te.y;
    float tdot = gx * wt0.x + gy * wt0.y
               + ie.x * wt1.x + ie.y * wt1.y
               + te.x * wt2.x + te.y * wt2.y
               + re.x * wt3.x + re.y * wt3.y;

    const float rx = rating * wr.x + br.x;
    const float ry = rating * wr.y + br.y;
    float sdot = rx * ws0.x + ry * ws0.y
               + ce.x * ws1.x + ce.y * ws1.y
               + se.x * ws2.x + se.y * ws2.y;

    // ---- 64-lane butterfly reduction of the three partials ----
    #pragma unroll
    for (int off = 32; off >= 1; off >>= 1) {
        ema  += __shfl_xor(ema,  off);
        tdot += __shfl_xor(tdot, off);
        sdot += __shfl_xor(sdot, off);
    }

    if (lane == 0) {
        const float pop = 1.f / (1.f + expf(-ema));

        float tv = tdot + b_time[0];
        tv = (tv >= 0.f) ? tv : 0.01f * tv;     // LeakyReLU(0.01)
        const float tim = 1.f / (1.f + expf(-tv));

        const float sv  = sdot + b_side[0];
        const float sid = 1.f / (1.f + expf(-sv));

        // softmax over att_w[3]
        const float a0 = att_w[0], a1 = att_w[1], a2 = att_w[2];
        const float m  = fmaxf(a0, fmaxf(a1, a2));
        const float e0 = expf(a0 - m), e1 = expf(a1 - m), e2 = expf(a2 - m);
        const float inv = 1.f / (e0 + e1 + e2);
        const float mix = (pop * e0 + tim * e1 + sid * e2) * inv;

        out[b]         = pop;
        out[B + b]     = tim;
        out[2 * B + b] = sid;
        out[3 * B + b] = mix;
    }
}

extern "C" void kernel_launch(void* const* d_in, const int* in_sizes, int n_in,
                              void* d_out, int out_size, void* d_ws, size_t ws_size,
                              hipStream_t stream) {
    const float* pop_history   = (const float*)d_in[0];
    const float* rating_number = (const float*)d_in[1];
    const int*   item_ids      = (const int*)d_in[2];
    const int*   times         = (const int*)d_in[3];
    const int*   release_times = (const int*)d_in[4];
    const int*   categories    = (const int*)d_in[5];
    const int*   stores        = (const int*)d_in[6];
    const float* item_emb      = (const float*)d_in[7];
    const float* cat_emb       = (const float*)d_in[8];
    const float* store_emb     = (const float*)d_in[9];
    const float* time_emb      = (const float*)d_in[10];
    const float* W_rating      = (const float*)d_in[11];
    const float* b_rating      = (const float*)d_in[12];
    const float* W_side        = (const float*)d_in[13];
    const float* b_side        = (const float*)d_in[14];
    const float* W_time        = (const float*)d_in[15];
    const float* b_time        = (const float*)d_in[16];
    const float* att_w         = (const float*)d_in[17];

    const int B = in_sizes[1];              // rating_number is [B]
    const int T = in_sizes[0] / B;          // pop_history is [B,T]

    const int rows_per_block = 4;           // 4 waves of 64
    const int grid = (B + rows_per_block - 1) / rows_per_block;
    pop_predict_kernel<<<grid, 256, 0, stream>>>(
        pop_history, rating_number, item_ids, times, release_times, categories,
        stores, item_emb, cat_emb, store_emb, time_emb,
        W_rating, b_rating, W_side, b_side, W_time, b_time, att_w,
        (float*)d_out, B, T);
}

// Round 3
// 10.177 us; speedup vs baseline: 1.1847x; 1.1505x over previous
//
#include <hip/hip_runtime.h>
#include <math.h>

#define ALPHA 0.1f
#define DDIM 128
#define KW 64   // EMA truncation: dropped mass 0.9^64 ~= 1.2e-3 -> <=3e-4 output err

__device__ __forceinline__ float dot4(float4 a, float4 b) {
    return a.x * b.x + a.y * b.y + a.z * b.z + a.w * b.w;
}

__global__ __launch_bounds__(256) void pop_predict_kernel(
    const float* __restrict__ pop_history,   // [B,T]
    const float* __restrict__ rating_number, // [B]
    const int*   __restrict__ item_ids,      // [B]
    const int*   __restrict__ times,         // [B]
    const int*   __restrict__ release_times, // [B]
    const int*   __restrict__ categories,    // [B]
    const int*   __restrict__ stores,        // [B]
    const float* __restrict__ item_emb,      // [NUM_ITEMS+1, D]
    const float* __restrict__ cat_emb,       // [NUM_CATS+1, D]
    const float* __restrict__ store_emb,     // [NUM_STORES, D]
    const float* __restrict__ time_emb,      // [MAX_TIME+1, D]
    const float* __restrict__ W_rating,      // [D]
    const float* __restrict__ b_rating,      // [D]
    const float* __restrict__ W_side,        // [3D]
    const float* __restrict__ b_side,        // [1]
    const float* __restrict__ W_time,        // [4D]
    const float* __restrict__ b_time,        // [1]
    const float* __restrict__ att_w,         // [3]
    float* __restrict__ out,                 // [4B] = pop | time | side | mix
    int B, int T)
{
    const int tid  = threadIdx.x;
    const int wave = tid >> 6;
    const int lane = tid & 63;
    const int g    = lane >> 4;   // row within wave (0..3)
    const int l    = lane & 15;   // lane within 16-lane row group
    const int b    = blockIdx.x * 16 + wave * 4 + g;
    if (b >= B) return;

    // ---- hoisted tiny-uniform loads: off the post-reduction critical path ----
    const float bt = b_time[0];
    const float bs = b_side[0];
    const float a0 = att_w[0], a1 = att_w[1], a2 = att_w[2];

    // ---- per-row scalars ----
    const int ti = times[b];
    const int ii = item_ids[b];
    const int ri = release_times[b];
    const int ci = categories[b];
    const int si = stores[b];
    const float rating = rating_number[b];

    // ---- EMA at tb = clip(ti-1,0), last KW terms; 4 consecutive k per lane ----
    // e_t = 0.9^t p_0 + sum_{k>=1} 0.1*0.9^(t-k) p_k ; exponent e = t-k = 63-(4l+j)
    int t = ti - 1; if (t < 0) t = 0;
    const float LOG2_09 = -0.15200309344504995f; // log2(0.9)
    const float* ph = pop_history + (size_t)b * (size_t)T;
    float ema = 0.f;
    #pragma unroll
    for (int j = 0; j < 4; ++j) {
        const int e = (KW - 1) - (l * 4 + j);    // lane-constant exponent
        const int k = t - e;
        float coef = ALPHA * exp2f((float)e * LOG2_09);
        if (k == 0) coef *= 10.f;                // p_0 term has no alpha factor
        if (k >= 0) ema += coef * ph[k];
    }

    // ---- embedding gathers + dots: lane owns dims [8l, 8l+8) as 2x float4 ----
    const int d0 = l * 8;
    const float4* ie4 = (const float4*)(item_emb  + (size_t)ii * DDIM + d0);
    const float4* te4 = (const float4*)(time_emb  + (size_t)ti * DDIM + d0);
    const float4* re4 = (const float4*)(time_emb  + (size_t)ri * DDIM + d0);
    const float4* ce4 = (const float4*)(cat_emb   + (size_t)ci * DDIM + d0);
    const float4* se4 = (const float4*)(store_emb + (size_t)si * DDIM + d0);
    const float4* wt0 = (const float4*)(W_time + d0);
    const float4* wt1 = (const float4*)(W_time + DDIM + d0);
    const float4* wt2 = (const float4*)(W_time + 2 * DDIM + d0);
    const float4* wt3 = (const float4*)(W_time + 3 * DDIM + d0);
    const float4* wr4 = (const float4*)(W_rating + d0);
    const float4* br4 = (const float4*)(b_rating + d0);
    const float4* ws0 = (const float4*)(W_side + d0);
    const float4* ws1 = (const float4*)(W_side + DDIM + d0);
    const float4* ws2 = (const float4*)(W_side + 2 * DDIM + d0);

    float tdot = 0.f, sdot = 0.f;
    #pragma unroll
    for (int h = 0; h < 2; ++h) {
        const float4 ie = ie4[h], te = te4[h], re = re4[h];
        const float4 ce = ce4[h], se = se4[h];
        const float4 g4 = make_float4(re.x - te.x, re.y - te.y, re.z - te.z, re.w - te.w);
        tdot += dot4(g4, wt0[h]) + dot4(ie, wt1[h]) + dot4(te, wt2[h]) + dot4(re, wt3[h]);
        const float4 w = wr4[h], c = br4[h];
        const float4 r = make_float4(rating * w.x + c.x, rating * w.y + c.y,
                                     rating * w.z + c.z, rating * w.w + c.w);
        sdot += dot4(r, ws0[h]) + dot4(ce, ws1[h]) + dot4(se, ws2[h]);
    }

    // ---- 16-lane butterfly reduction (4 levels) ----
    #pragma unroll
    for (int off = 8; off >= 1; off >>= 1) {
        ema  += __shfl_xor(ema,  off);
        tdot += __shfl_xor(tdot, off);
        sdot += __shfl_xor(sdot, off);
    }

    if (l == 0) {
        const float pop = 1.f / (1.f + expf(-ema));

        float tv = tdot + bt;
        tv = (tv >= 0.f) ? tv : 0.01f * tv;     // LeakyReLU(0.01)
        const float tim = 1.f / (1.f + expf(-tv));

        const float sv  = sdot + bs;
        const float sid = 1.f / (1.f + expf(-sv));

        const float m  = fmaxf(a0, fmaxf(a1, a2));
        const float e0 = expf(a0 - m), e1 = expf(a1 - m), e2 = expf(a2 - m);
        const float inv = 1.f / (e0 + e1 + e2);
        const float mix = (pop * e0 + tim * e1 + sid * e2) * inv;

        out[b]         = pop;
        out[B + b]     = tim;
        out[2 * B + b] = sid;
        out[3 * B + b] = mix;
    }
}

extern "C" void kernel_launch(void* const* d_in, const int* in_sizes, int n_in,
                              void* d_out, int out_size, void* d_ws, size_t ws_size,
                              hipStream_t stream) {
    const float* pop_history   = (const float*)d_in[0];
    const float* rating_number = (const float*)d_in[1];
    const int*   item_ids      = (const int*)d_in[2];
    const int*   times         = (const int*)d_in[3];
    const int*   release_times = (const int*)d_in[4];
    const int*   categories    = (const int*)d_in[5];
    const int*   stores        = (const int*)d_in[6];
    const float* item_emb      = (const float*)d_in[7];
    const float* cat_emb       = (const float*)d_in[8];
    const float* store_emb     = (const float*)d_in[9];
    const float* time_emb      = (const float*)d_in[10];
    const float* W_rating      = (const float*)d_in[11];
    const float* b_rating      = (const float*)d_in[12];
    const float* W_side        = (const float*)d_in[13];
    const float* b_side        = (const float*)d_in[14];
    const float* W_time        = (const float*)d_in[15];
    const float* b_time        = (const float*)d_in[16];
    const float* att_w         = (const float*)d_in[17];

    const int B = in_sizes[1];              // rating_number is [B]
    const int T = in_sizes[0] / B;          // pop_history is [B,T]

    const int rows_per_block = 16;          // 4 waves x 4 rows/wave
    const int grid = (B + rows_per_block - 1) / rows_per_block;
    pop_predict_kernel<<<grid, 256, 0, stream>>>(
        pop_history, rating_number, item_ids, times, release_times, categories,
        stores, item_emb, cat_emb, store_emb, time_emb,
        W_rating, b_rating, W_side, b_side, W_time, b_time, att_w,
        (float*)d_out, B, T);
}